// Round 13
// baseline (541.781 us; speedup 1.0000x reference)
//
#include <hip/hip_runtime.h>

#define N_ROWS 8192
#define IN_DIM 256
#define HID 128

typedef __attribute__((ext_vector_type(8))) short bf16x8;
typedef __attribute__((ext_vector_type(4))) float f32x4;

__device__ __forceinline__ unsigned short f2bf(float f) {
    union { float f; unsigned u; } v; v.f = f;
    unsigned r = (v.u + 0x7FFFu + ((v.u >> 16) & 1u)) >> 16;
    return (unsigned short)r;
}

__device__ __forceinline__ unsigned cvt_pk_bf16(float lo, float hi) {
    unsigned r;
    asm("v_cvt_pk_bf16_f32 %0, %1, %2" : "=v"(r) : "v"(lo), "v"(hi));
    return r;
}

// ---------------- pack: 4 weights [K][HO] -> WT bf16 [4*HO][K], biases -> B [4*HO]
__global__ void pack_weights(const float* __restrict__ W0, const float* __restrict__ W1,
                             const float* __restrict__ W2, const float* __restrict__ W3,
                             const float* __restrict__ b0, const float* __restrict__ b1,
                             const float* __restrict__ b2, const float* __restrict__ b3,
                             unsigned short* __restrict__ WT, float* __restrict__ B,
                             int K, int HO)
{
    int NT = 4 * HO;
    int idx = blockIdx.x * blockDim.x + threadIdx.x;
    if (idx < NT * K) {
        int n = idx / K, k = idx - n * K;
        int s = n / HO, sn = n - s * HO;
        const float* W = (s == 0) ? W0 : (s == 1) ? W1 : (s == 2) ? W2 : W3;
        WT[idx] = f2bf(W[k * HO + sn]);
    }
    if (idx < NT) {
        int s = idx / HO, sn = idx - s * HO;
        const float* b = (s == 0) ? b0 : (s == 1) ? b1 : (s == 2) ? b2 : b3;
        B[idx] = b[sn];
    }
}

__global__ void cast_x(const float* __restrict__ in, unsigned short* __restrict__ out, int n) {
    int i = blockIdx.x * blockDim.x + threadIdx.x;
    if (i < n) out[i] = f2bf(in[i]);
}

// ---------------- tiled bf16 transpose: in [R][C] -> out [C][R]
__global__ void transpose_bf16(const unsigned short* __restrict__ in,
                               unsigned short* __restrict__ out, int R, int C)
{
    __shared__ unsigned short t[32][33];
    const int tx = threadIdx.x, ty = threadIdx.y;
    const int r0 = blockIdx.y * 32, c0 = blockIdx.x * 32;
    #pragma unroll
    for (int j = 0; j < 32; j += 8)
        t[ty + j][tx] = in[(size_t)(r0 + ty + j) * C + c0 + tx];
    __syncthreads();
    #pragma unroll
    for (int j = 0; j < 32; j += 8)
        out[(size_t)(c0 + ty + j) * R + r0 + tx] = t[tx][ty + j];
}

// ---------------- fused projection GEMM: A[M][K] bf16 x WT[NT][K] -> q,k,v bf16 + skip f32
// q additionally scaled by qScale (attention scale * log2(e) folded in).
template<int K>
__global__ __launch_bounds__(256) void proj_gemm(
    const unsigned short* __restrict__ A, const unsigned short* __restrict__ WT,
    const float* __restrict__ bias,
    unsigned short* __restrict__ qo, unsigned short* __restrict__ ko,
    unsigned short* __restrict__ vo, float* __restrict__ skip,
    int NT, float qScale)
{
    const int lane = threadIdx.x & 63;
    const int wid = (blockIdx.x * blockDim.x + threadIdx.x) >> 6;
    const int nStrips = NT / 64;
    const int mTile = wid / nStrips;
    const int nBase = (wid - mTile * nStrips) * 64;
    const int l15 = lane & 15, lg = lane >> 4;
    const int HO = NT >> 2;

    f32x4 acc[4];
    #pragma unroll
    for (int c = 0; c < 4; ++c) acc[c] = f32x4{0.f, 0.f, 0.f, 0.f};

    const unsigned short* Ap = A + (size_t)(mTile * 16 + l15) * K + lg * 8;
    #pragma unroll
    for (int t = 0; t < K / 32; ++t) {
        bf16x8 a = *(const bf16x8*)(Ap + t * 32);
        #pragma unroll
        for (int c = 0; c < 4; ++c) {
            bf16x8 b = *(const bf16x8*)(WT + (size_t)(nBase + c * 16 + l15) * K + t * 32 + lg * 8);
            acc[c] = __builtin_amdgcn_mfma_f32_16x16x32_bf16(a, b, acc[c], 0, 0, 0);
        }
    }
    #pragma unroll
    for (int c = 0; c < 4; ++c) {
        int col = nBase + c * 16 + l15;
        int sec = col / HO, sc = col - sec * HO;
        float bv = bias[col];
        #pragma unroll
        for (int r = 0; r < 4; ++r) {
            int mrow = mTile * 16 + lg * 4 + r;
            float val = acc[c][r] + bv;
            size_t o = (size_t)mrow * HO + sc;
            if (sec == 0) qo[o] = f2bf(val * qScale);
            else if (sec == 1) ko[o] = f2bf(val);
            else if (sec == 2) vo[o] = f2bf(val);
            else skip[o] = val;
        }
    }
}

// ---------------- flash-attention partial over a K-chunk (exp2 domain).
// Round-7 base (Q2=2, 8 waves/512 thr, single-buffer K-LDS, no min-waves)
// + V REMOVED FROM LDS: the per-CU LDS pipe is the measured bottleneck
// (r12: co-residency didn't help because blocks share the LDS pipe).
// PV's V-fragments are preloaded per tile into registers DIRECTLY from
// global VT ([D][N]); all 8 waves read the same 16KB tile -> L1 serves
// 7/8 of it; loads are issued before the barrier+QK^T so L2 latency is
// hidden. LDS traffic per tile halves (K only); V staging writes and
// their bank conflicts disappear.
template<int D, int KB, int Q2>
__global__ __launch_bounds__(512) void attn_partial(
    const unsigned short* __restrict__ Qm,
    const unsigned short* __restrict__ Km,
    const unsigned short* __restrict__ VTg,
    float* __restrict__ accOut, float* __restrict__ mOut, float* __restrict__ lOut,
    int chunkLen)
{
    constexpr int TPB = 512;
    constexpr int LK = D + 8;    // 16B-granule-odd row stride
    constexpr int DT = D / 16;
    constexpr int CT = KB / 16;
    constexpr int KS = KB / 32;
    constexpr int QW = 16 * Q2;
    static_assert(KB * D / 8 / TPB == 2, "two K staging int4s per thread");
    __shared__ __align__(16) unsigned short Kl[KB * LK];

    const int tid = threadIdx.x;
    const int lane = tid & 63;
    const int w = tid >> 6;
    const int l15 = lane & 15, lg = lane >> 4;
    const int qrow = blockIdx.x * (8 * QW) + w * QW;
    const int kStart = blockIdx.y * chunkLen;
    const size_t NN = N_ROWS;

    // K staging coords (named scalars; idx0 = tid, idx1 = tid + 512)
    const int kr0 = tid / (D / 8), kc0 = tid - kr0 * (D / 8);
    const int kr1 = (tid + TPB) / (D / 8), kc1 = (tid + TPB) - kr1 * (D / 8);
    const int kg0 = kr0 * D + kc0 * 8, kl0 = kr0 * LK + kc0 * 8;
    const int kg1 = kr1 * D + kc1 * 8, kl1 = kr1 * LK + kc1 * 8;

    bf16x8 qf[Q2][D / 32];
    #pragma unroll
    for (int m = 0; m < Q2; ++m)
        #pragma unroll
        for (int t = 0; t < D / 32; ++t)
            qf[m][t] = *(const bf16x8*)(Qm + (size_t)(qrow + m * 16 + l15) * D + t * 32 + lg * 8);

    f32x4 acc[Q2][DT];   // out^T: acc[m][dt][r] = out[q][d=dt*16+lg*4+r]
    float mReg[Q2], lReg[Q2];
    #pragma unroll
    for (int m = 0; m < Q2; ++m) {
        #pragma unroll
        for (int dt = 0; dt < DT; ++dt) acc[m][dt] = f32x4{0.f, 0.f, 0.f, 0.f};
        mReg[m] = -__builtin_inff();
        lReg[m] = 0.f;
    }

    const int nt = chunkLen / KB;
    const unsigned short* Kp = Km + (size_t)kStart * D;
    // per-lane V base: row (dt*16 + l15), col (kGlob + ks*32 + lg*8)
    const unsigned short* Vbase = VTg + (size_t)l15 * NN + kStart + lg * 8;
    int4 pk0 = *(const int4*)(Kp + kg0);
    int4 pk1 = *(const int4*)(Kp + kg1);

    for (int t = 0; t < nt; ++t) {
        // issue V-tile loads early (independent of LDS; drain under barrier+QK^T)
        bf16x8 va[KS][DT];
        {
            const unsigned short* Vt = Vbase + t * KB;
            #pragma unroll
            for (int ks = 0; ks < KS; ++ks)
                #pragma unroll
                for (int dt = 0; dt < DT; ++dt)
                    va[ks][dt] = *(const bf16x8*)(Vt + (size_t)(dt * 16) * NN + ks * 32);
        }
        __syncthreads();
        *(int4*)(&Kl[kl0]) = pk0;
        *(int4*)(&Kl[kl1]) = pk1;
        __syncthreads();
        if (t + 1 < nt) {
            const unsigned short* KpN = Kp + (size_t)(t + 1) * KB * D;
            pk0 = *(const int4*)(KpN + kg0);
            pk1 = *(const int4*)(KpN + kg1);
        }
        // S^T = K @ Q^T: each K-frag read feeds Q2 MFMAs (log2 domain)
        f32x4 sT[Q2][CT];
        __builtin_amdgcn_s_setprio(1);
        #pragma unroll
        for (int c = 0; c < CT; ++c) {
            #pragma unroll
            for (int m = 0; m < Q2; ++m) sT[m][c] = f32x4{0.f, 0.f, 0.f, 0.f};
            #pragma unroll
            for (int tt = 0; tt < D / 32; ++tt) {
                bf16x8 kf = *(const bf16x8*)(&Kl[(c * 16 + l15) * LK + tt * 32 + lg * 8]);
                #pragma unroll
                for (int m = 0; m < Q2; ++m)
                    sT[m][c] = __builtin_amdgcn_mfma_f32_16x16x32_bf16(kf, qf[m][tt], sT[m][c], 0, 0, 0);
            }
        }
        __builtin_amdgcn_s_setprio(0);
        // per-lane softmax (q fixed per lane)
        float pmax[Q2];
        bool need = false;
        #pragma unroll
        for (int m = 0; m < Q2; ++m) {
            float v = sT[m][0][0];
            #pragma unroll
            for (int c = 0; c < CT; ++c)
                #pragma unroll
                for (int r = 0; r < 4; ++r) v = fmaxf(v, sT[m][c][r]);
            pmax[m] = v;
            need = need || (v > mReg[m] + 8.f);
        }
        if (__any(need)) {
            #pragma unroll
            for (int m = 0; m < Q2; ++m) {
                float v = pmax[m];
                v = fmaxf(v, __shfl_xor(v, 16));
                v = fmaxf(v, __shfl_xor(v, 32));
                float mN = fmaxf(mReg[m], v);
                float al = exp2f(mReg[m] - mN);
                mReg[m] = mN;
                lReg[m] *= al;
                #pragma unroll
                for (int dt = 0; dt < DT; ++dt) acc[m][dt] *= al;
            }
        }
        // P = exp2(S - m) in registers; pack bf16 pairs
        unsigned Wp[Q2][CT][2];
        #pragma unroll
        for (int m = 0; m < Q2; ++m) {
            float lsum = 0.f;
            #pragma unroll
            for (int c = 0; c < CT; ++c) {
                float p0 = exp2f(sT[m][c][0] - mReg[m]);
                float p1 = exp2f(sT[m][c][1] - mReg[m]);
                float p2 = exp2f(sT[m][c][2] - mReg[m]);
                float p3 = exp2f(sT[m][c][3] - mReg[m]);
                lsum += (p0 + p1) + (p2 + p3);
                Wp[m][c][0] = cvt_pk_bf16(p0, p1);
                Wp[m][c][1] = cvt_pk_bf16(p2, p3);
            }
            lReg[m] += lsum;
        }
        // PV: acc^T += V^T @ P^T; V-fragments already in registers (va).
        #pragma unroll
        for (int ks = 0; ks < KS; ++ks) {
            bf16x8 pbv[Q2];
            #pragma unroll
            for (int m = 0; m < Q2; ++m) {
                unsigned x0 = Wp[m][2 * ks][0], x1 = Wp[m][2 * ks][1];
                unsigned x2 = Wp[m][2 * ks + 1][0], x3 = Wp[m][2 * ks + 1][1];
                const bool g1 = (lg & 2) != 0, g0 = (lg & 1) != 0;
                unsigned s0 = g1 ? x0 : x2, s1 = g1 ? x1 : x3;
                unsigned r0 = __shfl_xor(s0, 32), r1 = __shfl_xor(s1, 32);
                unsigned k0 = g1 ? x2 : x0, k1 = g1 ? x3 : x1;
                unsigned t0 = (g0 != g1) ? k0 : r0, t1 = (g0 != g1) ? k1 : r1;
                unsigned q0 = __shfl_xor(t0, 16), q1 = __shfl_xor(t1, 16);
                union { unsigned u[4]; bf16x8 v; } pb;
                pb.u[0] = g0 ? q0 : (g1 ? r0 : k0);
                pb.u[1] = g0 ? q1 : (g1 ? r1 : k1);
                pb.u[2] = g0 ? (g1 ? k0 : r0) : q0;
                pb.u[3] = g0 ? (g1 ? k1 : r1) : q1;
                pbv[m] = pb.v;
            }
            __builtin_amdgcn_s_setprio(1);
            #pragma unroll
            for (int dt = 0; dt < DT; ++dt) {
                #pragma unroll
                for (int m = 0; m < Q2; ++m)
                    acc[m][dt] = __builtin_amdgcn_mfma_f32_16x16x32_bf16(va[ks][dt], pbv[m], acc[m][dt], 0, 0, 0);
            }
            __builtin_amdgcn_s_setprio(0);
        }
    }

    #pragma unroll
    for (int m = 0; m < Q2; ++m) {
        float lv = lReg[m];
        lv += __shfl_xor(lv, 16);
        lv += __shfl_xor(lv, 32);
        float* accRow = accOut + ((size_t)blockIdx.y * NN + qrow + m * 16 + l15) * D + lg * 4;
        #pragma unroll
        for (int dt = 0; dt < DT; ++dt)
            *(f32x4*)(accRow + dt * 16) = acc[m][dt];
        if (lg == 0) {
            mOut[blockIdx.y * NN + qrow + m * 16 + l15] = mReg[m];
            lOut[blockIdx.y * NN + qrow + m * 16 + l15] = lv;
        }
    }
}

// ---------------- combine K-split partials + skip (+ optional ELU -> bf16)
template<int D, bool ELU>
__global__ void combine_kernel(const float* __restrict__ acc, const float* __restrict__ mArr,
                               const float* __restrict__ lArr, const float* __restrict__ skip,
                               float* __restrict__ outF, unsigned short* __restrict__ outB,
                               int CH)
{
    const int row = blockIdx.x;
    const int d = threadIdx.x;
    const size_t NN = N_ROWS;
    float mStar = -__builtin_inff();
    for (int c = 0; c < CH; ++c) mStar = fmaxf(mStar, mArr[c * NN + row]);
    float denom = 0.f, val = 0.f;
    for (int c = 0; c < CH; ++c) {
        float wgt = exp2f(mArr[c * NN + row] - mStar);
        denom += wgt * lArr[c * NN + row];
        val += wgt * acc[((size_t)c * NN + row) * D + d];
    }
    float v = val / denom + skip[(size_t)row * D + d];
    if (ELU) {
        v = (v > 0.f) ? v : expm1f(v);
        outB[(size_t)row * D + d] = f2bf(v);
    } else {
        outF[(size_t)row * D + d] = v;
    }
}

extern "C" void kernel_launch(void* const* d_in, const int* in_sizes, int n_in,
                              void* d_out, int out_size, void* d_ws, size_t ws_size,
                              hipStream_t stream)
{
    (void)in_sizes; (void)n_in; (void)out_size;
    const float* x   = (const float*)d_in[0];
    const float* Wq1 = (const float*)d_in[4];
    const float* bq1 = (const float*)d_in[5];
    const float* Wk1 = (const float*)d_in[6];
    const float* bk1 = (const float*)d_in[7];
    const float* Wv1 = (const float*)d_in[8];
    const float* bv1 = (const float*)d_in[9];
    const float* Ws1 = (const float*)d_in[10];
    const float* bs1 = (const float*)d_in[11];
    const float* Wq4 = (const float*)d_in[12];
    const float* bq4 = (const float*)d_in[13];
    const float* Wk4 = (const float*)d_in[14];
    const float* bk4 = (const float*)d_in[15];
    const float* Wv4 = (const float*)d_in[16];
    const float* bv4 = (const float*)d_in[17];
    const float* Ws4 = (const float*)d_in[18];
    const float* bs4 = (const float*)d_in[19];
    float* out = (float*)d_out;

    const int N = N_ROWS;
    size_t off = 0;
    auto alloc = [&](size_t bytes) -> void* {
        void* p = (char*)d_ws + off;
        off = (off + bytes + 255) & ~(size_t)255;
        return p;
    };
    unsigned short* xb  = (unsigned short*)alloc((size_t)N * IN_DIM * 2);
    unsigned short* WT1 = (unsigned short*)alloc((size_t)512 * 256 * 2);
    float* B1           = (float*)alloc(512 * 4);
    unsigned short* WT4 = (unsigned short*)alloc((size_t)1024 * 128 * 2);
    float* B4           = (float*)alloc(1024 * 4);
    unsigned short* q1  = (unsigned short*)alloc((size_t)N * HID * 2);
    unsigned short* k1  = (unsigned short*)alloc((size_t)N * HID * 2);
    unsigned short* v1  = (unsigned short*)alloc((size_t)N * HID * 2);
    unsigned short* VT1g= (unsigned short*)alloc((size_t)HID * N * 2);
    float* skip1        = (float*)alloc((size_t)N * HID * 4);
    unsigned short* h1  = (unsigned short*)alloc((size_t)N * HID * 2);
    unsigned short* q4  = (unsigned short*)alloc((size_t)N * IN_DIM * 2);
    unsigned short* k4  = (unsigned short*)alloc((size_t)N * IN_DIM * 2);
    unsigned short* v4  = (unsigned short*)alloc((size_t)N * IN_DIM * 2);
    unsigned short* VT4g= (unsigned short*)alloc((size_t)IN_DIM * N * 2);
    float* skip4        = (float*)alloc((size_t)N * IN_DIM * 4);

    size_t fixedEnd = off;
    size_t perCH = (size_t)N * 4 * 4 + (size_t)N * HID * 4 + (size_t)N * IN_DIM * 4 + 4096;
    int CH = 8;
    while (CH > 1 && fixedEnd + (size_t)CH * perCH > ws_size) CH >>= 1;

    float* m1   = (float*)alloc((size_t)CH * N * 4);
    float* l1   = (float*)alloc((size_t)CH * N * 4);
    float* m2   = (float*)alloc((size_t)CH * N * 4);
    float* l2   = (float*)alloc((size_t)CH * N * 4);
    float* acc1 = (float*)alloc((size_t)CH * N * HID * 4);
    float* acc2 = (float*)alloc((size_t)CH * N * IN_DIM * 4);
    if (off > ws_size && CH == 1) acc2 = out;  // in-place combine is element-exact

    const float LOG2E = 1.4426950408889634f;
    const float qs1 = 0.088388347648318447f * LOG2E;  // 1/sqrt(128) * log2(e)
    const float qs2 = 0.0625f * LOG2E;                // 1/sqrt(256) * log2(e)

    // ---- pack weights + cast x
    pack_weights<<<dim3((512 * 256 + 255) / 256), dim3(256), 0, stream>>>(
        Wq1, Wk1, Wv1, Ws1, bq1, bk1, bv1, bs1, WT1, B1, 256, 128);
    pack_weights<<<dim3((1024 * 128 + 255) / 256), dim3(256), 0, stream>>>(
        Wq4, Wk4, Wv4, Ws4, bq4, bk4, bv4, bs4, WT4, B4, 128, 256);
    cast_x<<<dim3((N * IN_DIM + 255) / 256), dim3(256), 0, stream>>>(x, xb, N * IN_DIM);

    // ---- layer 1
    proj_gemm<256><<<dim3((N / 16) * (512 / 64) / 4), dim3(256), 0, stream>>>(
        xb, WT1, B1, q1, k1, v1, skip1, 512, qs1);
    transpose_bf16<<<dim3(HID / 32, N / 32), dim3(32, 8), 0, stream>>>(v1, VT1g, N, HID);
    attn_partial<128, 64, 2><<<dim3(N / 256, CH), dim3(512), 0, stream>>>(
        q1, k1, VT1g, acc1, m1, l1, N / CH);
    combine_kernel<128, true><<<dim3(N), dim3(128), 0, stream>>>(
        acc1, m1, l1, skip1, (float*)nullptr, h1, CH);

    // ---- layer 2
    proj_gemm<128><<<dim3((N / 16) * (1024 / 64) / 4), dim3(256), 0, stream>>>(
        h1, WT4, B4, q4, k4, v4, skip4, 1024, qs2);
    transpose_bf16<<<dim3(IN_DIM / 32, N / 32), dim3(32, 8), 0, stream>>>(v4, VT4g, N, IN_DIM);
    attn_partial<256, 32, 2><<<dim3(N / 256, CH), dim3(512), 0, stream>>>(
        q4, k4, VT4g, acc2, m2, l2, N / CH);
    combine_kernel<256, false><<<dim3(N), dim3(256), 0, stream>>>(
        acc2, m2, l2, skip4, out, (unsigned short*)nullptr, CH);
}

// Round 14
// 270.981 us; speedup vs baseline: 1.9993x; 1.9993x over previous
//
#include <hip/hip_runtime.h>

#define N_ROWS 8192
#define IN_DIM 256
#define HID 128

typedef __attribute__((ext_vector_type(8))) short bf16x8;
typedef __attribute__((ext_vector_type(4))) float f32x4;

__device__ __forceinline__ unsigned short f2bf(float f) {
    union { float f; unsigned u; } v; v.f = f;
    unsigned r = (v.u + 0x7FFFu + ((v.u >> 16) & 1u)) >> 16;
    return (unsigned short)r;
}

__device__ __forceinline__ unsigned cvt_pk_bf16(float lo, float hi) {
    unsigned r;
    asm("v_cvt_pk_bf16_f32 %0, %1, %2" : "=v"(r) : "v"(lo), "v"(hi));
    return r;
}

// ---------------- pack: 4 weights [K][HO] -> WT bf16 [4*HO][K], biases -> B [4*HO]
__global__ void pack_weights(const float* __restrict__ W0, const float* __restrict__ W1,
                             const float* __restrict__ W2, const float* __restrict__ W3,
                             const float* __restrict__ b0, const float* __restrict__ b1,
                             const float* __restrict__ b2, const float* __restrict__ b3,
                             unsigned short* __restrict__ WT, float* __restrict__ B,
                             int K, int HO)
{
    int NT = 4 * HO;
    int idx = blockIdx.x * blockDim.x + threadIdx.x;
    if (idx < NT * K) {
        int n = idx / K, k = idx - n * K;
        int s = n / HO, sn = n - s * HO;
        const float* W = (s == 0) ? W0 : (s == 1) ? W1 : (s == 2) ? W2 : W3;
        WT[idx] = f2bf(W[k * HO + sn]);
    }
    if (idx < NT) {
        int s = idx / HO, sn = idx - s * HO;
        const float* b = (s == 0) ? b0 : (s == 1) ? b1 : (s == 2) ? b2 : b3;
        B[idx] = b[sn];
    }
}

__global__ void cast_x(const float* __restrict__ in, unsigned short* __restrict__ out, int n) {
    int i = blockIdx.x * blockDim.x + threadIdx.x;
    if (i < n) out[i] = f2bf(in[i]);
}

// ---------------- tiled bf16 transpose: in [R][C] -> out [C][R]
__global__ void transpose_bf16(const unsigned short* __restrict__ in,
                               unsigned short* __restrict__ out, int R, int C)
{
    __shared__ unsigned short t[32][33];
    const int tx = threadIdx.x, ty = threadIdx.y;
    const int r0 = blockIdx.y * 32, c0 = blockIdx.x * 32;
    #pragma unroll
    for (int j = 0; j < 32; j += 8)
        t[ty + j][tx] = in[(size_t)(r0 + ty + j) * C + c0 + tx];
    __syncthreads();
    #pragma unroll
    for (int j = 0; j < 32; j += 8)
        out[(size_t)(c0 + ty + j) * R + r0 + tx] = t[tx][ty + j];
}

// ---------------- fused projection GEMM: A[M][K] bf16 x WT[NT][K] -> q,k,v bf16 + skip f32
// q additionally scaled by qScale (attention scale * log2(e) folded in).
template<int K>
__global__ __launch_bounds__(256) void proj_gemm(
    const unsigned short* __restrict__ A, const unsigned short* __restrict__ WT,
    const float* __restrict__ bias,
    unsigned short* __restrict__ qo, unsigned short* __restrict__ ko,
    unsigned short* __restrict__ vo, float* __restrict__ skip,
    int NT, float qScale)
{
    const int lane = threadIdx.x & 63;
    const int wid = (blockIdx.x * blockDim.x + threadIdx.x) >> 6;
    const int nStrips = NT / 64;
    const int mTile = wid / nStrips;
    const int nBase = (wid - mTile * nStrips) * 64;
    const int l15 = lane & 15, lg = lane >> 4;
    const int HO = NT >> 2;

    f32x4 acc[4];
    #pragma unroll
    for (int c = 0; c < 4; ++c) acc[c] = f32x4{0.f, 0.f, 0.f, 0.f};

    const unsigned short* Ap = A + (size_t)(mTile * 16 + l15) * K + lg * 8;
    #pragma unroll
    for (int t = 0; t < K / 32; ++t) {
        bf16x8 a = *(const bf16x8*)(Ap + t * 32);
        #pragma unroll
        for (int c = 0; c < 4; ++c) {
            bf16x8 b = *(const bf16x8*)(WT + (size_t)(nBase + c * 16 + l15) * K + t * 32 + lg * 8);
            acc[c] = __builtin_amdgcn_mfma_f32_16x16x32_bf16(a, b, acc[c], 0, 0, 0);
        }
    }
    #pragma unroll
    for (int c = 0; c < 4; ++c) {
        int col = nBase + c * 16 + l15;
        int sec = col / HO, sc = col - sec * HO;
        float bv = bias[col];
        #pragma unroll
        for (int r = 0; r < 4; ++r) {
            int mrow = mTile * 16 + lg * 4 + r;
            float val = acc[c][r] + bv;
            size_t o = (size_t)mrow * HO + sc;
            if (sec == 0) qo[o] = f2bf(val * qScale);
            else if (sec == 1) ko[o] = f2bf(val);
            else if (sec == 2) vo[o] = f2bf(val);
            else skip[o] = val;
        }
    }
}

// ---------------- flash-attention partial over a K-chunk (exp2 domain).
// FINAL (round-7 verified optimum, 271us total): swapped QK^T (lane owns
// q-row), per-lane softmax, in-register P butterfly, Q2=2 q-groups/wave,
// 8 waves (512 thr), single-buffer LDS, named-scalar reg prefetch,
// defer-max, setprio. Default launch_bounds (every min-waves variant and
// every register-heavier variant hit the hard ~256-VGPR allocatable
// ceiling and spilled to scratch: r3/r4/r8/r9/r13). Co-residency variants
// (r11/r12) regressed: blocks share the per-CU LDS pipe. LDS-bytes-
// reduction via global V (r13) regressed: L1 doesn't absorb the V re-reads
// and the va array spilled.
template<int D, int KB, int Q2>
__global__ __launch_bounds__(512) void attn_partial(
    const unsigned short* __restrict__ Qm,
    const unsigned short* __restrict__ Km,
    const unsigned short* __restrict__ VTg,
    float* __restrict__ accOut, float* __restrict__ mOut, float* __restrict__ lOut,
    int chunkLen)
{
    constexpr int TPB = 512;
    constexpr int LK = D + 8;    // 16B-granule-odd row strides
    constexpr int LV = KB + 8;
    constexpr int DT = D / 16;
    constexpr int CT = KB / 16;
    constexpr int KS = KB / 32;
    constexpr int QW = 16 * Q2;
    static_assert(KB * D / 8 / TPB == 2, "two K staging int4s per thread");
    static_assert(D * KB / 8 / TPB == 2, "two V staging int4s per thread");
    __shared__ __align__(16) unsigned short Kl[KB * LK];
    __shared__ __align__(16) unsigned short VTl[D * LV];

    const int tid = threadIdx.x;
    const int lane = tid & 63;
    const int w = tid >> 6;
    const int l15 = lane & 15, lg = lane >> 4;
    const int qrow = blockIdx.x * (8 * QW) + w * QW;
    const int kStart = blockIdx.y * chunkLen;
    const size_t NN = N_ROWS;

    // staging coords (named scalars; idx0 = tid, idx1 = tid + 512)
    const int kr0 = tid / (D / 8), kc0 = tid - kr0 * (D / 8);
    const int kr1 = (tid + TPB) / (D / 8), kc1 = (tid + TPB) - kr1 * (D / 8);
    const int kg0 = kr0 * D + kc0 * 8, kl0 = kr0 * LK + kc0 * 8;
    const int kg1 = kr1 * D + kc1 * 8, kl1 = kr1 * LK + kc1 * 8;
    const int vr0 = tid / (KB / 8), vc0 = tid - vr0 * (KB / 8);
    const int vr1 = (tid + TPB) / (KB / 8), vc1 = (tid + TPB) - vr1 * (KB / 8);
    const int vg0 = vr0 * (int)NN + vc0 * 8, vl0 = vr0 * LV + vc0 * 8;
    const int vg1 = vr1 * (int)NN + vc1 * 8, vl1 = vr1 * LV + vc1 * 8;

    bf16x8 qf[Q2][D / 32];
    #pragma unroll
    for (int m = 0; m < Q2; ++m)
        #pragma unroll
        for (int t = 0; t < D / 32; ++t)
            qf[m][t] = *(const bf16x8*)(Qm + (size_t)(qrow + m * 16 + l15) * D + t * 32 + lg * 8);

    f32x4 acc[Q2][DT];   // out^T: acc[m][dt][r] = out[q][d=dt*16+lg*4+r]
    float mReg[Q2], lReg[Q2];
    #pragma unroll
    for (int m = 0; m < Q2; ++m) {
        #pragma unroll
        for (int dt = 0; dt < DT; ++dt) acc[m][dt] = f32x4{0.f, 0.f, 0.f, 0.f};
        mReg[m] = -__builtin_inff();
        lReg[m] = 0.f;
    }

    const int nt = chunkLen / KB;
    const unsigned short* Kp = Km + (size_t)kStart * D;
    const unsigned short* Vp = VTg + kStart;
    int4 pk0 = *(const int4*)(Kp + kg0);
    int4 pk1 = *(const int4*)(Kp + kg1);
    int4 pv0 = *(const int4*)(Vp + vg0);
    int4 pv1 = *(const int4*)(Vp + vg1);

    for (int t = 0; t < nt; ++t) {
        __syncthreads();
        *(int4*)(&Kl[kl0]) = pk0;
        *(int4*)(&Kl[kl1]) = pk1;
        *(int4*)(&VTl[vl0]) = pv0;
        *(int4*)(&VTl[vl1]) = pv1;
        __syncthreads();
        if (t + 1 < nt) {
            const unsigned short* KpN = Kp + (size_t)(t + 1) * KB * D;
            const unsigned short* VpN = Vp + (t + 1) * KB;
            pk0 = *(const int4*)(KpN + kg0);
            pk1 = *(const int4*)(KpN + kg1);
            pv0 = *(const int4*)(VpN + vg0);
            pv1 = *(const int4*)(VpN + vg1);
        }
        // S^T = K @ Q^T: each K-frag read feeds Q2 MFMAs (log2 domain)
        f32x4 sT[Q2][CT];
        __builtin_amdgcn_s_setprio(1);
        #pragma unroll
        for (int c = 0; c < CT; ++c) {
            #pragma unroll
            for (int m = 0; m < Q2; ++m) sT[m][c] = f32x4{0.f, 0.f, 0.f, 0.f};
            #pragma unroll
            for (int tt = 0; tt < D / 32; ++tt) {
                bf16x8 kf = *(const bf16x8*)(&Kl[(c * 16 + l15) * LK + tt * 32 + lg * 8]);
                #pragma unroll
                for (int m = 0; m < Q2; ++m)
                    sT[m][c] = __builtin_amdgcn_mfma_f32_16x16x32_bf16(kf, qf[m][tt], sT[m][c], 0, 0, 0);
            }
        }
        __builtin_amdgcn_s_setprio(0);
        // per-lane softmax (q fixed per lane)
        float pmax[Q2];
        bool need = false;
        #pragma unroll
        for (int m = 0; m < Q2; ++m) {
            float v = sT[m][0][0];
            #pragma unroll
            for (int c = 0; c < CT; ++c)
                #pragma unroll
                for (int r = 0; r < 4; ++r) v = fmaxf(v, sT[m][c][r]);
            pmax[m] = v;
            need = need || (v > mReg[m] + 8.f);
        }
        if (__any(need)) {
            #pragma unroll
            for (int m = 0; m < Q2; ++m) {
                float v = pmax[m];
                v = fmaxf(v, __shfl_xor(v, 16));
                v = fmaxf(v, __shfl_xor(v, 32));
                float mN = fmaxf(mReg[m], v);
                float al = exp2f(mReg[m] - mN);
                mReg[m] = mN;
                lReg[m] *= al;
                #pragma unroll
                for (int dt = 0; dt < DT; ++dt) acc[m][dt] *= al;
            }
        }
        // P = exp2(S - m) in registers; pack bf16 pairs
        unsigned Wp[Q2][CT][2];
        #pragma unroll
        for (int m = 0; m < Q2; ++m) {
            float lsum = 0.f;
            #pragma unroll
            for (int c = 0; c < CT; ++c) {
                float p0 = exp2f(sT[m][c][0] - mReg[m]);
                float p1 = exp2f(sT[m][c][1] - mReg[m]);
                float p2 = exp2f(sT[m][c][2] - mReg[m]);
                float p3 = exp2f(sT[m][c][3] - mReg[m]);
                lsum += (p0 + p1) + (p2 + p3);
                Wp[m][c][0] = cvt_pk_bf16(p0, p1);
                Wp[m][c][1] = cvt_pk_bf16(p2, p3);
            }
            lReg[m] += lsum;
        }
        // PV: acc^T += V^T @ P^T; each V-frag read feeds Q2 MFMAs.
        #pragma unroll
        for (int ks = 0; ks < KS; ++ks) {
            bf16x8 pbv[Q2];
            #pragma unroll
            for (int m = 0; m < Q2; ++m) {
                unsigned x0 = Wp[m][2 * ks][0], x1 = Wp[m][2 * ks][1];
                unsigned x2 = Wp[m][2 * ks + 1][0], x3 = Wp[m][2 * ks + 1][1];
                const bool g1 = (lg & 2) != 0, g0 = (lg & 1) != 0;
                unsigned s0 = g1 ? x0 : x2, s1 = g1 ? x1 : x3;
                unsigned r0 = __shfl_xor(s0, 32), r1 = __shfl_xor(s1, 32);
                unsigned k0 = g1 ? x2 : x0, k1 = g1 ? x3 : x1;
                unsigned t0 = (g0 != g1) ? k0 : r0, t1 = (g0 != g1) ? k1 : r1;
                unsigned q0 = __shfl_xor(t0, 16), q1 = __shfl_xor(t1, 16);
                union { unsigned u[4]; bf16x8 v; } pb;
                pb.u[0] = g0 ? q0 : (g1 ? r0 : k0);
                pb.u[1] = g0 ? q1 : (g1 ? r1 : k1);
                pb.u[2] = g0 ? (g1 ? k0 : r0) : q0;
                pb.u[3] = g0 ? (g1 ? k1 : r1) : q1;
                pbv[m] = pb.v;
            }
            __builtin_amdgcn_s_setprio(1);
            #pragma unroll
            for (int dt = 0; dt < DT; ++dt) {
                bf16x8 va = *(const bf16x8*)(&VTl[(dt * 16 + l15) * LV + ks * 32 + lg * 8]);
                #pragma unroll
                for (int m = 0; m < Q2; ++m)
                    acc[m][dt] = __builtin_amdgcn_mfma_f32_16x16x32_bf16(va, pbv[m], acc[m][dt], 0, 0, 0);
            }
            __builtin_amdgcn_s_setprio(0);
        }
    }

    #pragma unroll
    for (int m = 0; m < Q2; ++m) {
        float lv = lReg[m];
        lv += __shfl_xor(lv, 16);
        lv += __shfl_xor(lv, 32);
        float* accRow = accOut + ((size_t)blockIdx.y * NN + qrow + m * 16 + l15) * D + lg * 4;
        #pragma unroll
        for (int dt = 0; dt < DT; ++dt)
            *(f32x4*)(accRow + dt * 16) = acc[m][dt];
        if (lg == 0) {
            mOut[blockIdx.y * NN + qrow + m * 16 + l15] = mReg[m];
            lOut[blockIdx.y * NN + qrow + m * 16 + l15] = lv;
        }
    }
}

// ---------------- combine K-split partials + skip (+ optional ELU -> bf16)
template<int D, bool ELU>
__global__ void combine_kernel(const float* __restrict__ acc, const float* __restrict__ mArr,
                               const float* __restrict__ lArr, const float* __restrict__ skip,
                               float* __restrict__ outF, unsigned short* __restrict__ outB,
                               int CH)
{
    const int row = blockIdx.x;
    const int d = threadIdx.x;
    const size_t NN = N_ROWS;
    float mStar = -__builtin_inff();
    for (int c = 0; c < CH; ++c) mStar = fmaxf(mStar, mArr[c * NN + row]);
    float denom = 0.f, val = 0.f;
    for (int c = 0; c < CH; ++c) {
        float wgt = exp2f(mArr[c * NN + row] - mStar);
        denom += wgt * lArr[c * NN + row];
        val += wgt * acc[((size_t)c * NN + row) * D + d];
    }
    float v = val / denom + skip[(size_t)row * D + d];
    if (ELU) {
        v = (v > 0.f) ? v : expm1f(v);
        outB[(size_t)row * D + d] = f2bf(v);
    } else {
        outF[(size_t)row * D + d] = v;
    }
}

extern "C" void kernel_launch(void* const* d_in, const int* in_sizes, int n_in,
                              void* d_out, int out_size, void* d_ws, size_t ws_size,
                              hipStream_t stream)
{
    (void)in_sizes; (void)n_in; (void)out_size;
    const float* x   = (const float*)d_in[0];
    const float* Wq1 = (const float*)d_in[4];
    const float* bq1 = (const float*)d_in[5];
    const float* Wk1 = (const float*)d_in[6];
    const float* bk1 = (const float*)d_in[7];
    const float* Wv1 = (const float*)d_in[8];
    const float* bv1 = (const float*)d_in[9];
    const float* Ws1 = (const float*)d_in[10];
    const float* bs1 = (const float*)d_in[11];
    const float* Wq4 = (const float*)d_in[12];
    const float* bq4 = (const float*)d_in[13];
    const float* Wk4 = (const float*)d_in[14];
    const float* bk4 = (const float*)d_in[15];
    const float* Wv4 = (const float*)d_in[16];
    const float* bv4 = (const float*)d_in[17];
    const float* Ws4 = (const float*)d_in[18];
    const float* bs4 = (const float*)d_in[19];
    float* out = (float*)d_out;

    const int N = N_ROWS;
    size_t off = 0;
    auto alloc = [&](size_t bytes) -> void* {
        void* p = (char*)d_ws + off;
        off = (off + bytes + 255) & ~(size_t)255;
        return p;
    };
    unsigned short* xb  = (unsigned short*)alloc((size_t)N * IN_DIM * 2);
    unsigned short* WT1 = (unsigned short*)alloc((size_t)512 * 256 * 2);
    float* B1           = (float*)alloc(512 * 4);
    unsigned short* WT4 = (unsigned short*)alloc((size_t)1024 * 128 * 2);
    float* B4           = (float*)alloc(1024 * 4);
    unsigned short* q1  = (unsigned short*)alloc((size_t)N * HID * 2);
    unsigned short* k1  = (unsigned short*)alloc((size_t)N * HID * 2);
    unsigned short* v1  = (unsigned short*)alloc((size_t)N * HID * 2);
    unsigned short* VT1g= (unsigned short*)alloc((size_t)HID * N * 2);
    float* skip1        = (float*)alloc((size_t)N * HID * 4);
    unsigned short* h1  = (unsigned short*)alloc((size_t)N * HID * 2);
    unsigned short* q4  = (unsigned short*)alloc((size_t)N * IN_DIM * 2);
    unsigned short* k4  = (unsigned short*)alloc((size_t)N * IN_DIM * 2);
    unsigned short* v4  = (unsigned short*)alloc((size_t)N * IN_DIM * 2);
    unsigned short* VT4g= (unsigned short*)alloc((size_t)IN_DIM * N * 2);
    float* skip4        = (float*)alloc((size_t)N * IN_DIM * 4);

    size_t fixedEnd = off;
    size_t perCH = (size_t)N * 4 * 4 + (size_t)N * HID * 4 + (size_t)N * IN_DIM * 4 + 4096;
    int CH = 8;
    while (CH > 1 && fixedEnd + (size_t)CH * perCH > ws_size) CH >>= 1;

    float* m1   = (float*)alloc((size_t)CH * N * 4);
    float* l1   = (float*)alloc((size_t)CH * N * 4);
    float* m2   = (float*)alloc((size_t)CH * N * 4);
    float* l2   = (float*)alloc((size_t)CH * N * 4);
    float* acc1 = (float*)alloc((size_t)CH * N * HID * 4);
    float* acc2 = (float*)alloc((size_t)CH * N * IN_DIM * 4);
    if (off > ws_size && CH == 1) acc2 = out;  // in-place combine is element-exact

    const float LOG2E = 1.4426950408889634f;
    const float qs1 = 0.088388347648318447f * LOG2E;  // 1/sqrt(128) * log2(e)
    const float qs2 = 0.0625f * LOG2E;                // 1/sqrt(256) * log2(e)

    // ---- pack weights + cast x
    pack_weights<<<dim3((512 * 256 + 255) / 256), dim3(256), 0, stream>>>(
        Wq1, Wk1, Wv1, Ws1, bq1, bk1, bv1, bs1, WT1, B1, 256, 128);
    pack_weights<<<dim3((1024 * 128 + 255) / 256), dim3(256), 0, stream>>>(
        Wq4, Wk4, Wv4, Ws4, bq4, bk4, bv4, bs4, WT4, B4, 128, 256);
    cast_x<<<dim3((N * IN_DIM + 255) / 256), dim3(256), 0, stream>>>(x, xb, N * IN_DIM);

    // ---- layer 1
    proj_gemm<256><<<dim3((N / 16) * (512 / 64) / 4), dim3(256), 0, stream>>>(
        xb, WT1, B1, q1, k1, v1, skip1, 512, qs1);
    transpose_bf16<<<dim3(HID / 32, N / 32), dim3(32, 8), 0, stream>>>(v1, VT1g, N, HID);
    attn_partial<128, 64, 2><<<dim3(N / 256, CH), dim3(512), 0, stream>>>(
        q1, k1, VT1g, acc1, m1, l1, N / CH);
    combine_kernel<128, true><<<dim3(N), dim3(128), 0, stream>>>(
        acc1, m1, l1, skip1, (float*)nullptr, h1, CH);

    // ---- layer 2
    proj_gemm<128><<<dim3((N / 16) * (1024 / 64) / 4), dim3(256), 0, stream>>>(
        h1, WT4, B4, q4, k4, v4, skip4, 1024, qs2);
    transpose_bf16<<<dim3(IN_DIM / 32, N / 32), dim3(32, 8), 0, stream>>>(v4, VT4g, N, IN_DIM);
    attn_partial<256, 32, 2><<<dim3(N / 256, CH), dim3(512), 0, stream>>>(
        q4, k4, VT4g, acc2, m2, l2, N / CH);
    combine_kernel<256, false><<<dim3(N), dim3(256), 0, stream>>>(
        acc2, m2, l2, skip4, out, (unsigned short*)nullptr, CH);
}